// Round 6
// baseline (248.621 us; speedup 1.0000x reference)
//
#include <hip/hip_runtime.h>
#include <hip/hip_bf16.h>

#define STAT_K 8
#define TOKEN_K 16

typedef short bf16x8 __attribute__((ext_vector_type(8)));
typedef float f32x4 __attribute__((ext_vector_type(4)));

__device__ inline ushort f2bf_rne(float x) {
    union { float f; unsigned u; } v; v.f = x;
    unsigned r = v.u + 0x7fff + ((v.u >> 16) & 1);
    return (ushort)(r >> 16);
}
__device__ inline float bf2f(ushort h) {
    union { unsigned u; float f; } v; v.u = ((unsigned)h) << 16;
    return v.f;
}

// ---------------------------------------------------------------------------
// K1: transpose + hi/lo-split the 6 weight matrices (one 6 MB sweep).
// ---------------------------------------------------------------------------
__global__ __launch_bounds__(256) void conv_w(
    const float* w0, const float* w1, const float* w2,
    const float* w3, const float* w4, const float* w5,
    ushort* wT)
{
    const int z = blockIdx.z;
    const float* srcs[6] = {w0, w1, w2, w3, w4, w5};
    const float* src = srcs[z];
    ushort* hi = wT + (size_t)z * 524288;
    ushort* lo = hi + 262144;
    __shared__ float t[32][33];
    const int c0 = blockIdx.x * 32, r0 = blockIdx.y * 32;
    const int tx = threadIdx.x & 31, ty = threadIdx.x >> 5;  // ty 0..7
    #pragma unroll
    for (int i = 0; i < 4; ++i)
        t[ty + 8 * i][tx] = src[(r0 + ty + 8 * i) * 512 + c0 + tx];
    __syncthreads();
    #pragma unroll
    for (int i = 0; i < 4; ++i) {
        float x = t[tx][ty + 8 * i];
        ushort h = f2bf_rne(x);
        int o = (c0 + ty + 8 * i) * 512 + r0 + tx;
        hi[o] = h;
        lo[o] = f2bf_rne(x - bf2f(h));
    }
}

// ---------------------------------------------------------------------------
// K2: all five projection GEMMs in one launch, with REGISTER PREFETCH:
// the next k-step's global loads are issued right after the staging barrier
// so HBM/L2 latency hides under the MFMA phase (T14 async-stage split).
// ---------------------------------------------------------------------------
__global__ __launch_bounds__(256) void gemm_all(
    const float* __restrict__ queries, const float* __restrict__ stat_keys,
    const float* __restrict__ token_keys, const float* __restrict__ values,
    const ushort* __restrict__ wT,
    float* __restrict__ q_stat, float* __restrict__ k_stat,
    float* __restrict__ q_tokf,
    ushort* __restrict__ k_tok, ushort* __restrict__ v_projT)
{
    __shared__ ushort smem[12800];   // 25.6 KB, unioned between variants
    const int tid = threadIdx.x;
    const int bid = blockIdx.x;
    const int wave = tid >> 6, lane = tid & 63;
    const int m16 = lane & 15, quad = lane >> 4;
    const int srow = tid >> 2, schunk = tid & 3;

    if (bid < 192) {
        // ---------------- split-precision 64x64 variant ----------------
        const int z = bid >> 6, t = bid & 63;
        const int row0 = (t >> 3) * 64, col0 = (t & 7) * 64;
        const float* A = (z == 1) ? stat_keys : queries;
        const ushort* Bh = wT + (size_t)z * 524288;
        const ushort* Bl = Bh + 262144;
        float* C = (z == 0) ? q_stat : (z == 1) ? k_stat : q_tokf;

        ushort* As_hi = smem;            // [64][40]
        ushort* As_lo = smem + 2560;
        ushort* Bs_hi = smem + 5120;
        ushort* Bs_lo = smem + 7680;
        const int wm = wave & 1, wn = wave >> 1;

        const float* ap = A + (size_t)(row0 + srow) * 512 + schunk * 8;
        const size_t bbase = (size_t)(col0 + srow) * 512 + schunk * 8;

        f32x4 acc[2][2];
        #pragma unroll
        for (int i = 0; i < 2; ++i)
            #pragma unroll
            for (int j = 0; j < 2; ++j)
                #pragma unroll
                for (int r = 0; r < 4; ++r) acc[i][j][r] = 0.f;

        // prologue loads (k0 = 0)
        float4 xa0 = ((const float4*)ap)[0];
        float4 xa1 = ((const float4*)ap)[1];
        uint4 rbh = *(const uint4*)(Bh + bbase);
        uint4 rbl = *(const uint4*)(Bl + bbase);

        for (int k0 = 0; k0 < 512; k0 += 32) {
            // stage from regs (convert A on the fly)
            ushort4 h0, l0, h1, l1;
            h0.x = f2bf_rne(xa0.x); l0.x = f2bf_rne(xa0.x - bf2f(h0.x));
            h0.y = f2bf_rne(xa0.y); l0.y = f2bf_rne(xa0.y - bf2f(h0.y));
            h0.z = f2bf_rne(xa0.z); l0.z = f2bf_rne(xa0.z - bf2f(h0.z));
            h0.w = f2bf_rne(xa0.w); l0.w = f2bf_rne(xa0.w - bf2f(h0.w));
            h1.x = f2bf_rne(xa1.x); l1.x = f2bf_rne(xa1.x - bf2f(h1.x));
            h1.y = f2bf_rne(xa1.y); l1.y = f2bf_rne(xa1.y - bf2f(h1.y));
            h1.z = f2bf_rne(xa1.z); l1.z = f2bf_rne(xa1.z - bf2f(h1.z));
            h1.w = f2bf_rne(xa1.w); l1.w = f2bf_rne(xa1.w - bf2f(h1.w));
            *(ushort4*)&As_hi[srow * 40 + schunk * 8]     = h0;
            *(ushort4*)&As_hi[srow * 40 + schunk * 8 + 4] = h1;
            *(ushort4*)&As_lo[srow * 40 + schunk * 8]     = l0;
            *(ushort4*)&As_lo[srow * 40 + schunk * 8 + 4] = l1;
            *(uint4*)&Bs_hi[srow * 40 + schunk * 8] = rbh;
            *(uint4*)&Bs_lo[srow * 40 + schunk * 8] = rbl;
            __syncthreads();

            // issue next k-step's loads (hide under MFMA)
            if (k0 < 480) {
                xa0 = ((const float4*)(ap + k0 + 32))[0];
                xa1 = ((const float4*)(ap + k0 + 32))[1];
                rbh = *(const uint4*)(Bh + bbase + k0 + 32);
                rbl = *(const uint4*)(Bl + bbase + k0 + 32);
            }

            bf16x8 af[2], bfv[2], afl[2], bfl[2];
            #pragma unroll
            for (int i = 0; i < 2; ++i) {
                af[i]  = *(const bf16x8*)&As_hi[(wm * 32 + i * 16 + m16) * 40 + quad * 8];
                bfv[i] = *(const bf16x8*)&Bs_hi[(wn * 32 + i * 16 + m16) * 40 + quad * 8];
                afl[i] = *(const bf16x8*)&As_lo[(wm * 32 + i * 16 + m16) * 40 + quad * 8];
                bfl[i] = *(const bf16x8*)&Bs_lo[(wn * 32 + i * 16 + m16) * 40 + quad * 8];
            }
            #pragma unroll
            for (int i = 0; i < 2; ++i)
                #pragma unroll
                for (int j = 0; j < 2; ++j) {
                    acc[i][j] = __builtin_amdgcn_mfma_f32_16x16x32_bf16(af[i],  bfv[j], acc[i][j], 0, 0, 0);
                    acc[i][j] = __builtin_amdgcn_mfma_f32_16x16x32_bf16(af[i],  bfl[j], acc[i][j], 0, 0, 0);
                    acc[i][j] = __builtin_amdgcn_mfma_f32_16x16x32_bf16(afl[i], bfv[j], acc[i][j], 0, 0, 0);
                }
            __syncthreads();
        }

        #pragma unroll
        for (int i = 0; i < 2; ++i)
            #pragma unroll
            for (int j = 0; j < 2; ++j) {
                int r0 = row0 + wm * 32 + i * 16 + quad * 4;
                int c = col0 + wn * 32 + j * 16 + m16;
                #pragma unroll
                for (int reg = 0; reg < 4; ++reg)
                    C[(size_t)(r0 + reg) * 512 + c] = acc[i][j][reg];
            }
    } else {
        // ---------------- token-path 64x256 variant (hi only) ----------------
        const int u = bid - 192;
        const int z2 = u >> 8, vv = u & 255;
        const int col0 = (vv & 1) * 256, row0 = (vv >> 1) * 64;
        const float* A = z2 ? values : token_keys;
        const ushort* Bh = wT + (size_t)(z2 ? 4 : 3) * 524288;

        ushort* As = smem;            // [64][40]
        ushort* Bs = smem + 2560;     // [256][40]
        const int r = row0 + srow;
        const float* ap = A + (size_t)((r >> 4) * 64 + 48 + (r & 15)) * 512 + schunk * 8;

        // B staging slots for this thread (4 x uint4)
        int brow[4], bchk[4];
        #pragma unroll
        for (int i = 0; i < 4; ++i) {
            int v = tid + i * 256;
            brow[i] = v >> 2; bchk[i] = v & 3;
        }

        f32x4 acc[4][4];
        #pragma unroll
        for (int i = 0; i < 4; ++i)
            #pragma unroll
            for (int j = 0; j < 4; ++j)
                #pragma unroll
                for (int rr = 0; rr < 4; ++rr) acc[i][j][rr] = 0.f;

        // prologue loads (k0 = 0)
        float4 xa0 = ((const float4*)ap)[0];
        float4 xa1 = ((const float4*)ap)[1];
        uint4 rb[4];
        #pragma unroll
        for (int i = 0; i < 4; ++i)
            rb[i] = *(const uint4*)(Bh + (size_t)(col0 + brow[i]) * 512 + bchk[i] * 8);

        for (int k0 = 0; k0 < 512; k0 += 32) {
            ushort4 h0, h1;
            h0.x = f2bf_rne(xa0.x); h0.y = f2bf_rne(xa0.y);
            h0.z = f2bf_rne(xa0.z); h0.w = f2bf_rne(xa0.w);
            h1.x = f2bf_rne(xa1.x); h1.y = f2bf_rne(xa1.y);
            h1.z = f2bf_rne(xa1.z); h1.w = f2bf_rne(xa1.w);
            *(ushort4*)&As[srow * 40 + schunk * 8]     = h0;
            *(ushort4*)&As[srow * 40 + schunk * 8 + 4] = h1;
            #pragma unroll
            for (int i = 0; i < 4; ++i)
                *(uint4*)&Bs[brow[i] * 40 + bchk[i] * 8] = rb[i];
            __syncthreads();

            // issue next k-step's loads (hide under MFMA)
            if (k0 < 480) {
                xa0 = ((const float4*)(ap + k0 + 32))[0];
                xa1 = ((const float4*)(ap + k0 + 32))[1];
                #pragma unroll
                for (int i = 0; i < 4; ++i)
                    rb[i] = *(const uint4*)(Bh + (size_t)(col0 + brow[i]) * 512 + k0 + 32 + bchk[i] * 8);
            }

            bf16x8 af[4], bf[4];
            #pragma unroll
            for (int i = 0; i < 4; ++i) {
                af[i] = *(const bf16x8*)&As[(i * 16 + m16) * 40 + quad * 8];
                bf[i] = *(const bf16x8*)&Bs[(wave * 64 + i * 16 + m16) * 40 + quad * 8];
            }
            #pragma unroll
            for (int i = 0; i < 4; ++i)
                #pragma unroll
                for (int j = 0; j < 4; ++j)
                    acc[i][j] = __builtin_amdgcn_mfma_f32_16x16x32_bf16(af[i], bf[j], acc[i][j], 0, 0, 0);
            __syncthreads();
        }

        #pragma unroll
        for (int i = 0; i < 4; ++i)
            #pragma unroll
            for (int j = 0; j < 4; ++j) {
                int rg = row0 + i * 16 + quad * 4;
                int c = col0 + wave * 64 + j * 16 + m16;
                if (z2 == 0) {
                    #pragma unroll
                    for (int reg = 0; reg < 4; ++reg)
                        k_tok[(size_t)(rg + reg) * 512 + c] = f2bf_rne(acc[i][j][reg]);
                } else {
                    int bb2 = rg >> 10, st = rg & 1023;
                    int hh = c >> 6, dd = c & 63;
                    ushort4 o4;
                    o4.x = f2bf_rne(acc[i][j][0]);
                    o4.y = f2bf_rne(acc[i][j][1]);
                    o4.z = f2bf_rne(acc[i][j][2]);
                    o4.w = f2bf_rne(acc[i][j][3]);
                    *(ushort4*)(v_projT + (((size_t)((bb2 * 8 + hh) * 64 + dd)) << 10) + st) = o4;
                }
            }
    }
}

// ---------------------------------------------------------------------------
// K3: stat scores + valid-len mask + top-8 + softmax -> DENSE stat_w
// [4096][64]. One wave per (b,h,q). (verified round 1/5)
// ---------------------------------------------------------------------------
__global__ __launch_bounds__(64) void stat_topk(
    const float* __restrict__ q_stat, const float* __restrict__ k_stat,
    const int* __restrict__ valid_lens,
    float* __restrict__ stat_wd)
{
    const int bid = blockIdx.x;           // b*512 + h*64 + q
    const int b = bid >> 9;
    const int hq = bid & 511;
    const int h = hq >> 6;
    const int q = hq & 63;
    const int lane = threadIdx.x;         // segment index s

    __shared__ float sq[64];
    sq[lane] = q_stat[(b * 64 + q) * 512 + h * 64 + lane];
    __syncthreads();

    const float4* kr = (const float4*)(k_stat + (b * 64 + lane) * 512 + h * 64);
    const float4* sq4 = (const float4*)sq;
    float sc = 0.f;
    #pragma unroll
    for (int i = 0; i < 16; ++i) {
        float4 a = sq4[i], kk = kr[i];
        sc += a.x * kk.x + a.y * kk.y + a.z * kk.z + a.w * kk.w;
    }
    sc *= 0.125f;
    if (lane >= valid_lens[b]) sc = -1e6f;

    const float sc_keep = sc;
    float my = sc;
    bool picked = false;
    float m0 = 0.f, den = 0.f;
    #pragma unroll
    for (int j = 0; j < STAT_K; ++j) {
        float v = my;
        int idx = lane;
        #pragma unroll
        for (int off = 32; off > 0; off >>= 1) {
            float ov = __shfl_down(v, off);
            int   oi = __shfl_down(idx, off);
            if (ov > v || (ov == v && oi < idx)) { v = ov; idx = oi; }
        }
        v = __shfl(v, 0);
        idx = __shfl(idx, 0);
        if (j == 0) m0 = v;
        den += __expf(v - m0);
        if (lane == idx) { my = -3e38f; picked = true; }
    }
    stat_wd[(size_t)bid * 64 + lane] = picked ? __expf(sc_keep - m0) / den : 0.f;
}

// ---------------------------------------------------------------------------
// K4: dense MFMA token attention, chunk-parallel. One block per
// (b,h,16-q slice,16-seg chunk) -> 1024 blocks, 4 waves. V fragments are
// issued at kernel top so L2/L3 latency hides under QK + softmax.
// ---------------------------------------------------------------------------
__global__ __launch_bounds__(256) void tok_attend(
    const float* __restrict__ q_tokf, const ushort* __restrict__ k_tok,
    const ushort* __restrict__ v_projT, const float* __restrict__ stat_wd,
    float* __restrict__ part)
{
    const int bid = blockIdx.x;
    const int ch = bid & 3, qb = (bid >> 2) & 3, bh = bid >> 4;
    const int b = bh >> 3, h = bh & 7;
    const int tid = threadIdx.x, wave = tid >> 6, lane = tid & 63;
    const int l15 = lane & 15, g = lane >> 4;
    const int q0 = qb * 16;

    __shared__ ushort qs_hi[16][72], qs_lo[16][72];       // q_tok hi/lo
    __shared__ float  sw16[16][17];                       // stat_w slice
    __shared__ ushort comb_hi[16][264], comb_lo[16][264]; // [q][st], swizzled

    // ---- issue all 8 V fragment loads NOW (consumed in PV at the end)
    bf16x8 vf[8];
    #pragma unroll
    for (int ks2 = 0; ks2 < 8; ++ks2)
        vf[ks2] = *(const bf16x8*)(v_projT +
            ((size_t)(bh * 64 + wave * 16 + l15) << 10) + ch * 256 + ks2 * 32 + g * 8);

    // ---- stage q slice (fp32 -> hi/lo bf16) and stat_w slice
    {
        const int qq = tid >> 4, c = (tid & 15) * 4;
        float4 x = *(const float4*)(q_tokf + (size_t)(b * 64 + q0 + qq) * 512 + h * 64 + c);
        ushort4 hx, lx;
        hx.x = f2bf_rne(x.x); lx.x = f2bf_rne(x.x - bf2f(hx.x));
        hx.y = f2bf_rne(x.y); lx.y = f2bf_rne(x.y - bf2f(hx.y));
        hx.z = f2bf_rne(x.z); lx.z = f2bf_rne(x.z - bf2f(hx.z));
        hx.w = f2bf_rne(x.w); lx.w = f2bf_rne(x.w - bf2f(hx.w));
        *(ushort4*)&qs_hi[qq][c] = hx;
        *(ushort4*)&qs_lo[qq][c] = lx;
        sw16[tid >> 4][tid & 15] =
            stat_wd[(size_t)bh * 4096 + (q0 + (tid >> 4)) * 64 + ch * 16 + (tid & 15)];
    }
    __syncthreads();

    const int swz = (l15 & 7) << 4;

    // ---- QK: this wave computes 4 segments (64 st) x 16 q
    const int sbase = ch * 16 + wave * 4;
    f32x4 sc[4];
    #pragma unroll
    for (int mt = 0; mt < 4; ++mt)
        #pragma unroll
        for (int rr = 0; rr < 4; ++rr) sc[mt][rr] = 0.f;

    #pragma unroll
    for (int ks2 = 0; ks2 < 2; ++ks2) {
        bf16x8 bhf = *(const bf16x8*)&qs_hi[l15][ks2 * 32 + g * 8];
        bf16x8 blf = *(const bf16x8*)&qs_lo[l15][ks2 * 32 + g * 8];
        #pragma unroll
        for (int mt = 0; mt < 4; ++mt) {
            const ushort* kp = k_tok +
                (size_t)(b * 1024 + (sbase + mt) * 16 + l15) * 512 + h * 64 + ks2 * 32 + g * 8;
            bf16x8 a = *(const bf16x8*)kp;
            sc[mt] = __builtin_amdgcn_mfma_f32_16x16x32_bf16(a, bhf, sc[mt], 0, 0, 0);
            sc[mt] = __builtin_amdgcn_mfma_f32_16x16x32_bf16(a, blf, sc[mt], 0, 0, 0);
        }
    }

    // ---- per-segment softmax over 16 tokens + comb write (hi/lo)
    #pragma unroll
    for (int mt = 0; mt < 4; ++mt) {
        float e0 = __expf(sc[mt][0] * 0.125f);
        float e1 = __expf(sc[mt][1] * 0.125f);
        float e2 = __expf(sc[mt][2] * 0.125f);
        float e3 = __expf(sc[mt][3] * 0.125f);
        float den = e0 + e1 + e2 + e3;
        den += __shfl_xor(den, 16);
        den += __shfl_xor(den, 32);
        float scl = sw16[l15][wave * 4 + mt] / den;
        ushort4 hx, lx;
        float c0 = e0 * scl; hx.x = f2bf_rne(c0); lx.x = f2bf_rne(c0 - bf2f(hx.x));
        float c1 = e1 * scl; hx.y = f2bf_rne(c1); lx.y = f2bf_rne(c1 - bf2f(hx.y));
        float c2 = e2 * scl; hx.z = f2bf_rne(c2); lx.z = f2bf_rne(c2 - bf2f(hx.z));
        float c3 = e3 * scl; hx.w = f2bf_rne(c3); lx.w = f2bf_rne(c3 - bf2f(hx.w));
        int colb = (((wave * 4 + mt) * 16 + g * 4) * 2) ^ swz;
        *(ushort4*)((char*)&comb_hi[l15][0] + colb) = hx;
        *(ushort4*)((char*)&comb_lo[l15][0] + colb) = lx;
    }
    __syncthreads();

    // ---- PV over this chunk (K = 256 st); wave owns 16-d block
    f32x4 accd;
    #pragma unroll
    for (int rr = 0; rr < 4; ++rr) accd[rr] = 0.f;

    #pragma unroll
    for (int ks2 = 0; ks2 < 8; ++ks2) {
        int colb = ((ks2 * 32 + g * 8) * 2) ^ swz;
        bf16x8 bhf = *(const bf16x8*)((const char*)&comb_hi[l15][0] + colb);
        bf16x8 blf = *(const bf16x8*)((const char*)&comb_lo[l15][0] + colb);
        accd = __builtin_amdgcn_mfma_f32_16x16x32_bf16(vf[ks2], bhf, accd, 0, 0, 0);
        accd = __builtin_amdgcn_mfma_f32_16x16x32_bf16(vf[ks2], blf, accd, 0, 0, 0);
    }

    // ---- partial write: lane holds d = wave*16 + g*4 + rr, q = q0 + l15
    *(f32x4*)(part + ((size_t)(ch * 512 + b * 64 + q0 + l15) * 512)
                    + h * 64 + wave * 16 + g * 4) = accd;
}

// ---------------------------------------------------------------------------
// K5: out = (sum_ch part[ch]) @ Wo(hi/lo planes), 512x512x512 -> fp32.
// A summed + split in registers during staging; register prefetch on all
// global loads.
// ---------------------------------------------------------------------------
__global__ __launch_bounds__(256) void gemm_out(
    const float* __restrict__ part,
    const ushort* __restrict__ Bh, const ushort* __restrict__ Bl,
    float* __restrict__ C)
{
    __shared__ ushort As[2][64][40];
    __shared__ ushort Bs[2][64][40];
    const int tid = threadIdx.x;
    const int row0 = blockIdx.y * 64, col0 = blockIdx.x * 64;
    const int wave = tid >> 6, lane = tid & 63;
    const int wm = wave & 1, wn = wave >> 1;
    const int m16 = lane & 15, quad = lane >> 4;
    const int srow = tid >> 2, schunk = tid & 3;

    const float* pb = part + (size_t)(row0 + srow) * 512 + schunk * 8;
    const size_t bbase = (size_t)(col0 + srow) * 512 + schunk * 8;

    f32x4 acc[2][2];
    #pragma unroll
    for (int i = 0; i < 2; ++i)
        #pragma unroll
        for (int j = 0; j < 2; ++j)
            #pragma unroll
            for (int r = 0; r < 4; ++r) acc[i][j][r] = 0.f;

    // prologue loads (k0 = 0)
    float4 pa[4][2];
    #pragma unroll
    for (int c = 0; c < 4; ++c) {
        const float4* p4 = (const float4*)(pb + (size_t)c * 262144);
        pa[c][0] = p4[0]; pa[c][1] = p4[1];
    }
    uint4 rbh = *(const uint4*)(Bh + bbase);
    uint4 rbl = *(const uint4*)(Bl + bbase);

    for (int k0 = 0; k0 < 512; k0 += 32) {
        // A: sum 4 chunk partials, split hi/lo
        float s[8];
        #pragma unroll
        for (int e = 0; e < 8; ++e) s[e] = 0.f;
        #pragma unroll
        for (int c = 0; c < 4; ++c) {
            s[0] += pa[c][0].x; s[1] += pa[c][0].y;
            s[2] += pa[c][0].z; s[3] += pa[c][0].w;
            s[4] += pa[c][1].x; s[5] += pa[c][1].y;
            s[6] += pa[c][1].z; s[7] += pa[c][1].w;
        }
        ushort hv[8], lv[8];
        #pragma unroll
        for (int e = 0; e < 8; ++e) {
            hv[e] = f2bf_rne(s[e]);
            lv[e] = f2bf_rne(s[e] - bf2f(hv[e]));
        }
        *(ushort4*)&As[0][srow][schunk * 8]     = *(ushort4*)&hv[0];
        *(ushort4*)&As[0][srow][schunk * 8 + 4] = *(ushort4*)&hv[4];
        *(ushort4*)&As[1][srow][schunk * 8]     = *(ushort4*)&lv[0];
        *(ushort4*)&As[1][srow][schunk * 8 + 4] = *(ushort4*)&lv[4];
        *(uint4*)&Bs[0][srow][schunk * 8] = rbh;
        *(uint4*)&Bs[1][srow][schunk * 8] = rbl;
        __syncthreads();

        // issue next k-step's loads
        if (k0 < 480) {
            #pragma unroll
            for (int c = 0; c < 4; ++c) {
                const float4* p4 = (const float4*)(pb + k0 + 32 + (size_t)c * 262144);
                pa[c][0] = p4[0]; pa[c][1] = p4[1];
            }
            rbh = *(const uint4*)(Bh + bbase + k0 + 32);
            rbl = *(const uint4*)(Bl + bbase + k0 + 32);
        }

        bf16x8 af[2], bf[2], afl[2], bfl[2];
        #pragma unroll
        for (int i = 0; i < 2; ++i) {
            af[i]  = *(const bf16x8*)&As[0][wm * 32 + i * 16 + m16][quad * 8];
            bf[i]  = *(const bf16x8*)&Bs[0][wn * 32 + i * 16 + m16][quad * 8];
            afl[i] = *(const bf16x8*)&As[1][wm * 32 + i * 16 + m16][quad * 8];
            bfl[i] = *(const bf16x8*)&Bs[1][wn * 32 + i * 16 + m16][quad * 8];
        }
        #pragma unroll
        for (int i = 0; i < 2; ++i)
            #pragma unroll
            for (int j = 0; j < 2; ++j) {
                acc[i][j] = __builtin_amdgcn_mfma_f32_16x16x32_bf16(af[i], bf[j], acc[i][j], 0, 0, 0);
                acc[i][j] = __builtin_amdgcn_mfma_f32_16x16x32_bf16(af[i], bfl[j], acc[i][j], 0, 0, 0);
                acc[i][j] = __builtin_amdgcn_mfma_f32_16x16x32_bf16(afl[i], bf[j], acc[i][j], 0, 0, 0);
            }
        __syncthreads();
    }

    #pragma unroll
    for (int i = 0; i < 2; ++i)
        #pragma unroll
        for (int j = 0; j < 2; ++j) {
            int r0 = row0 + wm * 32 + i * 16 + quad * 4;
            int c = col0 + wn * 32 + j * 16 + m16;
            #pragma unroll
            for (int reg = 0; reg < 4; ++reg)
                C[(size_t)(r0 + reg) * 512 + c] = acc[i][j][reg];
        }
}

extern "C" void kernel_launch(void* const* d_in, const int* in_sizes, int n_in,
                              void* d_out, int out_size, void* d_ws, size_t ws_size,
                              hipStream_t stream) {
    const float* queries    = (const float*)d_in[0];
    const float* stat_keys  = (const float*)d_in[1];
    const float* token_keys = (const float*)d_in[2];
    const float* values     = (const float*)d_in[3];
    const int*   valid_lens = (const int*)d_in[4];
    const float* Wq_stat    = (const float*)d_in[5];
    const float* Wq_token   = (const float*)d_in[6];
    const float* Wk_stat    = (const float*)d_in[7];
    const float* Wk_token   = (const float*)d_in[8];
    const float* Wv         = (const float*)d_in[9];
    const float* Wo         = (const float*)d_in[10];

    char* w = (char*)d_ws;
    ushort* wT      = (ushort*)(w + 0);          // 6 MB: 6 x (hi+lo) x 262144
    float*  q_stat  = (float*)(w + 6291456);     // 1 MB fp32 [512][512]
    float*  k_stat  = (float*)(w + 7340032);     // 1 MB
    float*  q_tokf  = (float*)(w + 8388608);     // 1 MB
    ushort* k_tok   = (ushort*)(w + 9437184);    // 8 MB bf16 [8192][512]
    ushort* v_projT = (ushort*)(w + 17825792);   // 8 MB bf16 [64][64][1024]
    float*  stat_wd = (float*)(w + 26214400);    // 1 MB dense [4096][64]
    float*  part    = (float*)(w + 27262976);    // 4 MB fp32 [4][512][512]

    // weight order in wT: 0=Wq_stat 1=Wk_stat 2=Wq_token 3=Wk_token 4=Wv 5=Wo
    ushort* wo_h = wT + 5 * 524288, *wo_l = wo_h + 262144;

    // K1: weight transpose + hi/lo split (once)
    conv_w<<<dim3(16, 16, 6), 256, 0, stream>>>(
        Wq_stat, Wk_stat, Wq_token, Wk_token, Wv, Wo, wT);

    // K2: all five projection GEMMs, one launch, reg-prefetch
    gemm_all<<<704, 256, 0, stream>>>(
        queries, stat_keys, token_keys, values, wT,
        q_stat, k_stat, q_tokf, k_tok, v_projT);

    // K3: stat top-8 + softmax -> dense stat_w
    stat_topk<<<4096, 64, 0, stream>>>(q_stat, k_stat, valid_lens, stat_wd);

    // K4: chunk-parallel dense token attention -> fp32 partials
    tok_attend<<<1024, 256, 0, stream>>>(q_tokf, k_tok, v_projT, stat_wd, part);

    // K5: output projection (sums partials in A-staging, reg-prefetch)
    gemm_out<<<dim3(8, 8), 256, 0, stream>>>(part, wo_h, wo_l, (float*)d_out);
}

// Round 7
// 225.658 us; speedup vs baseline: 1.1018x; 1.1018x over previous
//
#include <hip/hip_runtime.h>
#include <hip/hip_bf16.h>

#define STAT_K 8
#define TOKEN_K 16

typedef short bf16x8 __attribute__((ext_vector_type(8)));
typedef float f32x4 __attribute__((ext_vector_type(4)));

__device__ inline ushort f2bf_rne(float x) {
    union { float f; unsigned u; } v; v.f = x;
    unsigned r = v.u + 0x7fff + ((v.u >> 16) & 1);
    return (ushort)(r >> 16);
}
__device__ inline float bf2f(ushort h) {
    union { unsigned u; float f; } v; v.u = ((unsigned)h) << 16;
    return v.f;
}

// ---------------------------------------------------------------------------
// K1: transpose + hi/lo-split the 6 weight matrices (one 6 MB sweep).
// ---------------------------------------------------------------------------
__global__ __launch_bounds__(256) void conv_w(
    const float* w0, const float* w1, const float* w2,
    const float* w3, const float* w4, const float* w5,
    ushort* wT)
{
    const int z = blockIdx.z;
    const float* srcs[6] = {w0, w1, w2, w3, w4, w5};
    const float* src = srcs[z];
    ushort* hi = wT + (size_t)z * 524288;
    ushort* lo = hi + 262144;
    __shared__ float t[32][33];
    const int c0 = blockIdx.x * 32, r0 = blockIdx.y * 32;
    const int tx = threadIdx.x & 31, ty = threadIdx.x >> 5;  // ty 0..7
    #pragma unroll
    for (int i = 0; i < 4; ++i)
        t[ty + 8 * i][tx] = src[(r0 + ty + 8 * i) * 512 + c0 + tx];
    __syncthreads();
    #pragma unroll
    for (int i = 0; i < 4; ++i) {
        float x = t[tx][ty + 8 * i];
        ushort h = f2bf_rne(x);
        int o = (c0 + ty + 8 * i) * 512 + r0 + tx;
        hi[o] = h;
        lo[o] = f2bf_rne(x - bf2f(h));
    }
}

// ---------------------------------------------------------------------------
// K2: all five projection GEMMs in one launch (round-5 verified structure;
// token-path tile shrunk 64x256 -> 64x128 for 2x grid parallelism and
// halved register pressure; no register prefetch — round 6 showed it spills).
//   bid <  192  : split-precision 64x64 tiles (fp32 out)
//   bid >= 192  : token-path 64x128 tiles, hi-only bf16 (1024 blocks)
// ---------------------------------------------------------------------------
__global__ __launch_bounds__(256) void gemm_all(
    const float* __restrict__ queries, const float* __restrict__ stat_keys,
    const float* __restrict__ token_keys, const float* __restrict__ values,
    const ushort* __restrict__ wT,
    float* __restrict__ q_stat, float* __restrict__ k_stat,
    float* __restrict__ q_tokf,
    ushort* __restrict__ k_tok, ushort* __restrict__ v_projT)
{
    __shared__ ushort smem[10240];   // 20.5 KB, unioned between variants
    const int tid = threadIdx.x;
    const int bid = blockIdx.x;
    const int wave = tid >> 6, lane = tid & 63;
    const int m16 = lane & 15, quad = lane >> 4;
    const int srow = tid >> 2, schunk = tid & 3;

    if (bid < 192) {
        // ---------------- split-precision 64x64 variant ----------------
        const int z = bid >> 6, t = bid & 63;
        const int row0 = (t >> 3) * 64, col0 = (t & 7) * 64;
        const float* A = (z == 1) ? stat_keys : queries;
        const ushort* Bh = wT + (size_t)z * 524288;
        const ushort* Bl = Bh + 262144;
        float* C = (z == 0) ? q_stat : (z == 1) ? k_stat : q_tokf;

        ushort* As_hi = smem;            // [64][40]
        ushort* As_lo = smem + 2560;
        ushort* Bs_hi = smem + 5120;
        ushort* Bs_lo = smem + 7680;
        const int wm = wave & 1, wn = wave >> 1;

        f32x4 acc[2][2];
        #pragma unroll
        for (int i = 0; i < 2; ++i)
            #pragma unroll
            for (int j = 0; j < 2; ++j)
                #pragma unroll
                for (int r = 0; r < 4; ++r) acc[i][j][r] = 0.f;

        for (int k0 = 0; k0 < 512; k0 += 32) {
            const float* ap = A + (size_t)(row0 + srow) * 512 + k0 + schunk * 8;
            float4 x0 = ((const float4*)ap)[0];
            float4 x1 = ((const float4*)ap)[1];
            ushort4 h0, l0, h1, l1;
            h0.x = f2bf_rne(x0.x); l0.x = f2bf_rne(x0.x - bf2f(h0.x));
            h0.y = f2bf_rne(x0.y); l0.y = f2bf_rne(x0.y - bf2f(h0.y));
            h0.z = f2bf_rne(x0.z); l0.z = f2bf_rne(x0.z - bf2f(h0.z));
            h0.w = f2bf_rne(x0.w); l0.w = f2bf_rne(x0.w - bf2f(h0.w));
            h1.x = f2bf_rne(x1.x); l1.x = f2bf_rne(x1.x - bf2f(h1.x));
            h1.y = f2bf_rne(x1.y); l1.y = f2bf_rne(x1.y - bf2f(h1.y));
            h1.z = f2bf_rne(x1.z); l1.z = f2bf_rne(x1.z - bf2f(h1.z));
            h1.w = f2bf_rne(x1.w); l1.w = f2bf_rne(x1.w - bf2f(h1.w));
            *(ushort4*)&As_hi[srow * 40 + schunk * 8]     = h0;
            *(ushort4*)&As_hi[srow * 40 + schunk * 8 + 4] = h1;
            *(ushort4*)&As_lo[srow * 40 + schunk * 8]     = l0;
            *(ushort4*)&As_lo[srow * 40 + schunk * 8 + 4] = l1;

            const size_t boff = (size_t)(col0 + srow) * 512 + k0 + schunk * 8;
            *(uint4*)&Bs_hi[srow * 40 + schunk * 8] = *(const uint4*)(Bh + boff);
            *(uint4*)&Bs_lo[srow * 40 + schunk * 8] = *(const uint4*)(Bl + boff);
            __syncthreads();

            bf16x8 af[2], bfv[2], afl[2], bfl[2];
            #pragma unroll
            for (int i = 0; i < 2; ++i) {
                af[i]  = *(const bf16x8*)&As_hi[(wm * 32 + i * 16 + m16) * 40 + quad * 8];
                bfv[i] = *(const bf16x8*)&Bs_hi[(wn * 32 + i * 16 + m16) * 40 + quad * 8];
                afl[i] = *(const bf16x8*)&As_lo[(wm * 32 + i * 16 + m16) * 40 + quad * 8];
                bfl[i] = *(const bf16x8*)&Bs_lo[(wn * 32 + i * 16 + m16) * 40 + quad * 8];
            }
            #pragma unroll
            for (int i = 0; i < 2; ++i)
                #pragma unroll
                for (int j = 0; j < 2; ++j) {
                    acc[i][j] = __builtin_amdgcn_mfma_f32_16x16x32_bf16(af[i],  bfv[j], acc[i][j], 0, 0, 0);
                    acc[i][j] = __builtin_amdgcn_mfma_f32_16x16x32_bf16(af[i],  bfl[j], acc[i][j], 0, 0, 0);
                    acc[i][j] = __builtin_amdgcn_mfma_f32_16x16x32_bf16(afl[i], bfv[j], acc[i][j], 0, 0, 0);
                }
            __syncthreads();
        }

        #pragma unroll
        for (int i = 0; i < 2; ++i)
            #pragma unroll
            for (int j = 0; j < 2; ++j) {
                int r0 = row0 + wm * 32 + i * 16 + quad * 4;
                int c = col0 + wn * 32 + j * 16 + m16;
                #pragma unroll
                for (int reg = 0; reg < 4; ++reg)
                    C[(size_t)(r0 + reg) * 512 + c] = acc[i][j][reg];
            }
    } else {
        // ---------------- token-path 64x128 variant (hi only) ----------------
        const int u = bid - 192;
        const int z2 = u >> 9, vv = u & 511;             // 512 blocks per z2
        const int col0 = (vv & 3) * 128, row0 = (vv >> 2) * 64;
        const float* A = z2 ? values : token_keys;
        const ushort* Bh = wT + (size_t)(z2 ? 4 : 3) * 524288;

        ushort* As = smem;            // [64][40]  = 2560 ush
        ushort* Bs = smem + 2560;     // [128][40] = 5120 ush
        const int r = row0 + srow;
        const size_t arow = (size_t)((r >> 4) * 64 + 48 + (r & 15)) * 512;

        f32x4 acc[4][2];
        #pragma unroll
        for (int i = 0; i < 4; ++i)
            #pragma unroll
            for (int j = 0; j < 2; ++j)
                #pragma unroll
                for (int rr = 0; rr < 4; ++rr) acc[i][j][rr] = 0.f;

        for (int k0 = 0; k0 < 512; k0 += 32) {
            const float* ap = A + arow + k0 + schunk * 8;
            float4 x0 = ((const float4*)ap)[0];
            float4 x1 = ((const float4*)ap)[1];
            ushort4 h0, h1;
            h0.x = f2bf_rne(x0.x); h0.y = f2bf_rne(x0.y);
            h0.z = f2bf_rne(x0.z); h0.w = f2bf_rne(x0.w);
            h1.x = f2bf_rne(x1.x); h1.y = f2bf_rne(x1.y);
            h1.z = f2bf_rne(x1.z); h1.w = f2bf_rne(x1.w);
            *(ushort4*)&As[srow * 40 + schunk * 8]     = h0;
            *(ushort4*)&As[srow * 40 + schunk * 8 + 4] = h1;

            #pragma unroll
            for (int i = 0; i < 2; ++i) {
                int v = tid + i * 256;
                int brow = v >> 2, bchunk = v & 3;
                *(uint4*)&Bs[brow * 40 + bchunk * 8] =
                    *(const uint4*)(Bh + (size_t)(col0 + brow) * 512 + k0 + bchunk * 8);
            }
            __syncthreads();

            bf16x8 af[4], bf[2];
            #pragma unroll
            for (int i = 0; i < 4; ++i)
                af[i] = *(const bf16x8*)&As[(i * 16 + m16) * 40 + quad * 8];
            #pragma unroll
            for (int j = 0; j < 2; ++j)
                bf[j] = *(const bf16x8*)&Bs[(wave * 32 + j * 16 + m16) * 40 + quad * 8];
            #pragma unroll
            for (int i = 0; i < 4; ++i)
                #pragma unroll
                for (int j = 0; j < 2; ++j)
                    acc[i][j] = __builtin_amdgcn_mfma_f32_16x16x32_bf16(af[i], bf[j], acc[i][j], 0, 0, 0);
            __syncthreads();
        }

        #pragma unroll
        for (int i = 0; i < 4; ++i)
            #pragma unroll
            for (int j = 0; j < 2; ++j) {
                int rg = row0 + i * 16 + quad * 4;
                int c = col0 + wave * 32 + j * 16 + m16;
                if (z2 == 0) {
                    #pragma unroll
                    for (int reg = 0; reg < 4; ++reg)
                        k_tok[(size_t)(rg + reg) * 512 + c] = f2bf_rne(acc[i][j][reg]);
                } else {
                    int bb2 = rg >> 10, st = rg & 1023;
                    int hh = c >> 6, dd = c & 63;
                    ushort4 o4;
                    o4.x = f2bf_rne(acc[i][j][0]);
                    o4.y = f2bf_rne(acc[i][j][1]);
                    o4.z = f2bf_rne(acc[i][j][2]);
                    o4.w = f2bf_rne(acc[i][j][3]);
                    *(ushort4*)(v_projT + (((size_t)((bb2 * 8 + hh) * 64 + dd)) << 10) + st) = o4;
                }
            }
    }
}

// ---------------------------------------------------------------------------
// K3: stat scores + valid-len mask + top-8 + softmax -> DENSE stat_w
// [4096][64]. One wave per (b,h,q). (verified)
// ---------------------------------------------------------------------------
__global__ __launch_bounds__(64) void stat_topk(
    const float* __restrict__ q_stat, const float* __restrict__ k_stat,
    const int* __restrict__ valid_lens,
    float* __restrict__ stat_wd)
{
    const int bid = blockIdx.x;           // b*512 + h*64 + q
    const int b = bid >> 9;
    const int hq = bid & 511;
    const int h = hq >> 6;
    const int q = hq & 63;
    const int lane = threadIdx.x;         // segment index s

    __shared__ float sq[64];
    sq[lane] = q_stat[(b * 64 + q) * 512 + h * 64 + lane];
    __syncthreads();

    const float4* kr = (const float4*)(k_stat + (b * 64 + lane) * 512 + h * 64);
    const float4* sq4 = (const float4*)sq;
    float sc = 0.f;
    #pragma unroll
    for (int i = 0; i < 16; ++i) {
        float4 a = sq4[i], kk = kr[i];
        sc += a.x * kk.x + a.y * kk.y + a.z * kk.z + a.w * kk.w;
    }
    sc *= 0.125f;
    if (lane >= valid_lens[b]) sc = -1e6f;

    const float sc_keep = sc;
    float my = sc;
    bool picked = false;
    float m0 = 0.f, den = 0.f;
    #pragma unroll
    for (int j = 0; j < STAT_K; ++j) {
        float v = my;
        int idx = lane;
        #pragma unroll
        for (int off = 32; off > 0; off >>= 1) {
            float ov = __shfl_down(v, off);
            int   oi = __shfl_down(idx, off);
            if (ov > v || (ov == v && oi < idx)) { v = ov; idx = oi; }
        }
        v = __shfl(v, 0);
        idx = __shfl(idx, 0);
        if (j == 0) m0 = v;
        den += __expf(v - m0);
        if (lane == idx) { my = -3e38f; picked = true; }
    }
    stat_wd[(size_t)bid * 64 + lane] = picked ? __expf(sc_keep - m0) / den : 0.f;
}

// ---------------------------------------------------------------------------
// K4: dense MFMA token attention, chunk-parallel (round-5 verified).
// One block per (b,h,16-q slice,16-seg chunk) -> 1024 blocks, 4 waves.
// ---------------------------------------------------------------------------
__global__ __launch_bounds__(256) void tok_attend(
    const float* __restrict__ q_tokf, const ushort* __restrict__ k_tok,
    const ushort* __restrict__ v_projT, const float* __restrict__ stat_wd,
    float* __restrict__ part)
{
    const int bid = blockIdx.x;
    const int ch = bid & 3, qb = (bid >> 2) & 3, bh = bid >> 4;
    const int b = bh >> 3, h = bh & 7;
    const int tid = threadIdx.x, wave = tid >> 6, lane = tid & 63;
    const int l15 = lane & 15, g = lane >> 4;
    const int q0 = qb * 16;

    __shared__ ushort qs_hi[16][72], qs_lo[16][72];       // q_tok hi/lo
    __shared__ float  sw16[16][17];                       // stat_w slice
    __shared__ ushort comb_hi[16][264], comb_lo[16][264]; // [q][st], swizzled

    // ---- stage q slice (fp32 -> hi/lo bf16) and stat_w slice
    {
        const int qq = tid >> 4, c = (tid & 15) * 4;
        float4 x = *(const float4*)(q_tokf + (size_t)(b * 64 + q0 + qq) * 512 + h * 64 + c);
        ushort4 hx, lx;
        hx.x = f2bf_rne(x.x); lx.x = f2bf_rne(x.x - bf2f(hx.x));
        hx.y = f2bf_rne(x.y); lx.y = f2bf_rne(x.y - bf2f(hx.y));
        hx.z = f2bf_rne(x.z); lx.z = f2bf_rne(x.z - bf2f(hx.z));
        hx.w = f2bf_rne(x.w); lx.w = f2bf_rne(x.w - bf2f(hx.w));
        *(ushort4*)&qs_hi[qq][c] = hx;
        *(ushort4*)&qs_lo[qq][c] = lx;
        sw16[tid >> 4][tid & 15] =
            stat_wd[(size_t)bh * 4096 + (q0 + (tid >> 4)) * 64 + ch * 16 + (tid & 15)];
    }
    __syncthreads();

    const int swz = (l15 & 7) << 4;

    // ---- QK: this wave computes 4 segments (64 st) x 16 q
    const int sbase = ch * 16 + wave * 4;
    f32x4 sc[4];
    #pragma unroll
    for (int mt = 0; mt < 4; ++mt)
        #pragma unroll
        for (int rr = 0; rr < 4; ++rr) sc[mt][rr] = 0.f;

    #pragma unroll
    for (int ks2 = 0; ks2 < 2; ++ks2) {
        bf16x8 bhf = *(const bf16x8*)&qs_hi[l15][ks2 * 32 + g * 8];
        bf16x8 blf = *(const bf16x8*)&qs_lo[l15][ks2 * 32 + g * 8];
        #pragma unroll
        for (int mt = 0; mt < 4; ++mt) {
            const ushort* kp = k_tok +
                (size_t)(b * 1024 + (sbase + mt) * 16 + l15) * 512 + h * 64 + ks2 * 32 + g * 8;
            bf16x8 a = *(const bf16x8*)kp;
            sc[mt] = __builtin_amdgcn_mfma_f32_16x16x32_bf16(a, bhf, sc[mt], 0, 0, 0);
            sc[mt] = __builtin_amdgcn_mfma_f32_16x16x32_bf16(a, blf, sc[mt], 0, 0, 0);
        }
    }

    // ---- per-segment softmax over 16 tokens + comb write (hi/lo)
    #pragma unroll
    for (int mt = 0; mt < 4; ++mt) {
        float e0 = __expf(sc[mt][0] * 0.125f);
        float e1 = __expf(sc[mt][1] * 0.125f);
        float e2 = __expf(sc[mt][2] * 0.125f);
        float e3 = __expf(sc[mt][3] * 0.125f);
        float den = e0 + e1 + e2 + e3;
        den += __shfl_xor(den, 16);
        den += __shfl_xor(den, 32);
        float scl = sw16[l15][wave * 4 + mt] / den;
        ushort4 hx, lx;
        float c0 = e0 * scl; hx.x = f2bf_rne(c0); lx.x = f2bf_rne(c0 - bf2f(hx.x));
        float c1 = e1 * scl; hx.y = f2bf_rne(c1); lx.y = f2bf_rne(c1 - bf2f(hx.y));
        float c2 = e2 * scl; hx.z = f2bf_rne(c2); lx.z = f2bf_rne(c2 - bf2f(hx.z));
        float c3 = e3 * scl; hx.w = f2bf_rne(c3); lx.w = f2bf_rne(c3 - bf2f(hx.w));
        int colb = (((wave * 4 + mt) * 16 + g * 4) * 2) ^ swz;
        *(ushort4*)((char*)&comb_hi[l15][0] + colb) = hx;
        *(ushort4*)((char*)&comb_lo[l15][0] + colb) = lx;
    }
    __syncthreads();

    // ---- PV over this chunk (K = 256 st); wave owns 16-d block
    f32x4 accd;
    #pragma unroll
    for (int rr = 0; rr < 4; ++rr) accd[rr] = 0.f;

    #pragma unroll
    for (int ks2 = 0; ks2 < 8; ++ks2) {
        const ushort* vp = v_projT +
            ((size_t)(bh * 64 + wave * 16 + l15) << 10) + ch * 256 + ks2 * 32 + g * 8;
        bf16x8 a = *(const bf16x8*)vp;
        int colb = ((ks2 * 32 + g * 8) * 2) ^ swz;
        bf16x8 bhf = *(const bf16x8*)((const char*)&comb_hi[l15][0] + colb);
        bf16x8 blf = *(const bf16x8*)((const char*)&comb_lo[l15][0] + colb);
        accd = __builtin_amdgcn_mfma_f32_16x16x32_bf16(a, bhf, accd, 0, 0, 0);
        accd = __builtin_amdgcn_mfma_f32_16x16x32_bf16(a, blf, accd, 0, 0, 0);
    }

    // ---- partial write: lane holds d = wave*16 + g*4 + rr, q = q0 + l15
    *(f32x4*)(part + ((size_t)(ch * 512 + b * 64 + q0 + l15) * 512)
                    + h * 64 + wave * 16 + g * 4) = accd;
}

// ---------------------------------------------------------------------------
// K5: out = (sum_ch part[ch]) @ Wo(hi/lo planes), 512x512x512 -> fp32.
// (round-5 verified; no register prefetch)
// ---------------------------------------------------------------------------
__global__ __launch_bounds__(256) void gemm_out(
    const float* __restrict__ part,
    const ushort* __restrict__ Bh, const ushort* __restrict__ Bl,
    float* __restrict__ C)
{
    __shared__ ushort As[2][64][40];
    __shared__ ushort Bs[2][64][40];
    const int tid = threadIdx.x;
    const int row0 = blockIdx.y * 64, col0 = blockIdx.x * 64;
    const int wave = tid >> 6, lane = tid & 63;
    const int wm = wave & 1, wn = wave >> 1;
    const int m16 = lane & 15, quad = lane >> 4;
    const int srow = tid >> 2, schunk = tid & 3;

    f32x4 acc[2][2];
    #pragma unroll
    for (int i = 0; i < 2; ++i)
        #pragma unroll
        for (int j = 0; j < 2; ++j)
            #pragma unroll
            for (int r = 0; r < 4; ++r) acc[i][j][r] = 0.f;

    for (int k0 = 0; k0 < 512; k0 += 32) {
        // A: sum 4 chunk partials, split hi/lo
        const float* pb = part + (size_t)(row0 + srow) * 512 + k0 + schunk * 8;
        float s[8];
        #pragma unroll
        for (int e = 0; e < 8; ++e) s[e] = 0.f;
        #pragma unroll
        for (int c = 0; c < 4; ++c) {
            const float4* p4 = (const float4*)(pb + (size_t)c * 262144);
            float4 a0 = p4[0], a1 = p4[1];
            s[0] += a0.x; s[1] += a0.y; s[2] += a0.z; s[3] += a0.w;
            s[4] += a1.x; s[5] += a1.y; s[6] += a1.z; s[7] += a1.w;
        }
        ushort hv[8], lv[8];
        #pragma unroll
        for (int e = 0; e < 8; ++e) {
            hv[e] = f2bf_rne(s[e]);
            lv[e] = f2bf_rne(s[e] - bf2f(hv[e]));
        }
        *(ushort4*)&As[0][srow][schunk * 8]     = *(ushort4*)&hv[0];
        *(ushort4*)&As[0][srow][schunk * 8 + 4] = *(ushort4*)&hv[4];
        *(ushort4*)&As[1][srow][schunk * 8]     = *(ushort4*)&lv[0];
        *(ushort4*)&As[1][srow][schunk * 8 + 4] = *(ushort4*)&lv[4];

        const size_t boff = (size_t)(col0 + srow) * 512 + k0 + schunk * 8;
        *(uint4*)&Bs[0][srow][schunk * 8] = *(const uint4*)(Bh + boff);
        *(uint4*)&Bs[1][srow][schunk * 8] = *(const uint4*)(Bl + boff);
        __syncthreads();

        bf16x8 af[2], bf[2], afl[2], bfl[2];
        #pragma unroll
        for (int i = 0; i < 2; ++i) {
            af[i]  = *(const bf16x8*)&As[0][wm * 32 + i * 16 + m16][quad * 8];
            bf[i]  = *(const bf16x8*)&Bs[0][wn * 32 + i * 16 + m16][quad * 8];
            afl[i] = *(const bf16x8*)&As[1][wm * 32 + i * 16 + m16][quad * 8];
            bfl[i] = *(const bf16x8*)&Bs[1][wn * 32 + i * 16 + m16][quad * 8];
        }
        #pragma unroll
        for (int i = 0; i < 2; ++i)
            #pragma unroll
            for (int j = 0; j < 2; ++j) {
                acc[i][j] = __builtin_amdgcn_mfma_f32_16x16x32_bf16(af[i], bf[j], acc[i][j], 0, 0, 0);
                acc[i][j] = __builtin_amdgcn_mfma_f32_16x16x32_bf16(af[i], bfl[j], acc[i][j], 0, 0, 0);
                acc[i][j] = __builtin_amdgcn_mfma_f32_16x16x32_bf16(afl[i], bf[j], acc[i][j], 0, 0, 0);
            }
        __syncthreads();
    }

    #pragma unroll
    for (int i = 0; i < 2; ++i)
        #pragma unroll
        for (int j = 0; j < 2; ++j) {
            int r0 = row0 + wm * 32 + i * 16 + quad * 4;
            int c = col0 + wn * 32 + j * 16 + m16;
            #pragma unroll
            for (int reg = 0; reg < 4; ++reg)
                C[(size_t)(r0 + reg) * 512 + c] = acc[i][j][reg];
        }
}

extern "C" void kernel_launch(void* const* d_in, const int* in_sizes, int n_in,
                              void* d_out, int out_size, void* d_ws, size_t ws_size,
                              hipStream_t stream) {
    const float* queries    = (const float*)d_in[0];
    const float* stat_keys  = (const float*)d_in[1];
    const float* token_keys = (const float*)d_in[2];
    const float* values     = (const float*)d_in[3];
    const int*   valid_lens = (const int*)d_in[4];
    const float* Wq_stat    = (const float*)d_in[5];
    const float* Wq_token   = (const float*)d_in[6];
    const float* Wk_stat    = (const float*)d_in[7];
    const float* Wk_token   = (const float*)d_in[8];
    const float* Wv         = (const float*)d_in[9];
    const float* Wo         = (const float*)d_in[10];

    char* w = (char*)d_ws;
    ushort* wT      = (ushort*)(w + 0);          // 6 MB: 6 x (hi+lo) x 262144
    float*  q_stat  = (float*)(w + 6291456);     // 1 MB fp32 [512][512]
    float*  k_stat  = (float*)(w + 7340032);     // 1 MB
    float*  q_tokf  = (float*)(w + 8388608);     // 1 MB
    ushort* k_tok   = (ushort*)(w + 9437184);    // 8 MB bf16 [8192][512]
    ushort* v_projT = (ushort*)(w + 17825792);   // 8 MB bf16 [64][64][1024]
    float*  stat_wd = (float*)(w + 26214400);    // 1 MB dense [4096][64]
    float*  part    = (float*)(w + 27262976);    // 4 MB fp32 [4][512][512]

    // weight order in wT: 0=Wq_stat 1=Wk_stat 2=Wq_token 3=Wk_token 4=Wv 5=Wo
    ushort* wo_h = wT + 5 * 524288, *wo_l = wo_h + 262144;

    // K1: weight transpose + hi/lo split (once)
    conv_w<<<dim3(16, 16, 6), 256, 0, stream>>>(
        Wq_stat, Wk_stat, Wq_token, Wk_token, Wv, Wo, wT);

    // K2: all five projection GEMMs, one launch (1216 blocks)
    gemm_all<<<1216, 256, 0, stream>>>(
        queries, stat_keys, token_keys, values, wT,
        q_stat, k_stat, q_tokf, k_tok, v_projT);

    // K3: stat top-8 + softmax -> dense stat_w
    stat_topk<<<4096, 64, 0, stream>>>(q_stat, k_stat, valid_lens, stat_wd);

    // K4: chunk-parallel dense token attention -> fp32 partials
    tok_attend<<<1024, 256, 0, stream>>>(q_tokf, k_tok, v_projT, stat_wd, part);

    // K5: output projection (sums partials in A-staging)
    gemm_out<<<dim3(8, 8), 256, 0, stream>>>(part, wo_h, wo_l, (float*)d_out);
}

// Round 8
// 222.348 us; speedup vs baseline: 1.1182x; 1.0149x over previous
//
#include <hip/hip_runtime.h>
#include <hip/hip_bf16.h>

#define STAT_K 8
#define TOKEN_K 16

typedef short bf16x8 __attribute__((ext_vector_type(8)));
typedef float f32x4 __attribute__((ext_vector_type(4)));

__device__ inline ushort f2bf_rne(float x) {
    union { float f; unsigned u; } v; v.f = x;
    unsigned r = v.u + 0x7fff + ((v.u >> 16) & 1);
    return (ushort)(r >> 16);
}
__device__ inline float bf2f(ushort h) {
    union { unsigned u; float f; } v; v.u = ((unsigned)h) << 16;
    return v.f;
}

// ---------------------------------------------------------------------------
// K1: ALL conversions in one launch (linear bid):
//   bid <  1536 : 6 weights -> transpose + hi/lo split (wT planes)
//   bid <  2048 : queries / stat_keys -> hi/lo split (no transpose)
//   bid >= 2048 : token_keys / values last-16 rows -> dense bf16 [8192][512]
// ---------------------------------------------------------------------------
__global__ __launch_bounds__(256) void conv_all(
    const float* w0, const float* w1, const float* w2,
    const float* w3, const float* w4, const float* w5,
    const float* queries, const float* stat_keys,
    const float* token_keys, const float* values,
    ushort* wT, ushort* q_hi, ushort* q_lo, ushort* sk_hi, ushort* sk_lo,
    ushort* tk_bf, ushort* v_bf)
{
    const int bid = blockIdx.x;
    if (bid < 1536) {
        const int z = bid >> 8, t = bid & 255;
        const float* srcs[6] = {w0, w1, w2, w3, w4, w5};
        const float* src = srcs[z];
        ushort* hi = wT + (size_t)z * 524288;
        ushort* lo = hi + 262144;
        __shared__ float tt[32][33];
        const int c0 = (t & 15) * 32, r0 = (t >> 4) * 32;
        const int tx = threadIdx.x & 31, ty = threadIdx.x >> 5;  // ty 0..7
        #pragma unroll
        for (int i = 0; i < 4; ++i)
            tt[ty + 8 * i][tx] = src[(r0 + ty + 8 * i) * 512 + c0 + tx];
        __syncthreads();
        #pragma unroll
        for (int i = 0; i < 4; ++i) {
            float x = tt[tx][ty + 8 * i];
            ushort h = f2bf_rne(x);
            int o = (c0 + ty + 8 * i) * 512 + r0 + tx;
            hi[o] = h;
            lo[o] = f2bf_rne(x - bf2f(h));
        }
    } else if (bid < 2048) {
        const int u = bid - 1536;
        const int z = u >> 8, t = u & 255;
        const float* src = z ? stat_keys : queries;
        ushort* hi = z ? sk_hi : q_hi;
        ushort* lo = z ? sk_lo : q_lo;
        const int base = t * 1024 + threadIdx.x * 4;
        float4 x = *(const float4*)(src + base);
        ushort4 h, l;
        h.x = f2bf_rne(x.x); l.x = f2bf_rne(x.x - bf2f(h.x));
        h.y = f2bf_rne(x.y); l.y = f2bf_rne(x.y - bf2f(h.y));
        h.z = f2bf_rne(x.z); l.z = f2bf_rne(x.z - bf2f(h.z));
        h.w = f2bf_rne(x.w); l.w = f2bf_rne(x.w - bf2f(h.w));
        *(ushort4*)(hi + base) = h;
        *(ushort4*)(lo + base) = l;
    } else {
        const int u = bid - 2048;
        const int z = u >> 11, t = u & 2047;       // 2048 blocks per tensor
        const float* src = z ? values : token_keys;
        ushort* dst = z ? v_bf : tk_bf;
        const int r = t * 4 + (threadIdx.x >> 6);  // dense dst row 0..8191
        const int c = (threadIdx.x & 63) * 8;
        const float* sp = src + (size_t)((r >> 4) * 64 + 48 + (r & 15)) * 512 + c;
        float4 x0 = ((const float4*)sp)[0];
        float4 x1 = ((const float4*)sp)[1];
        ushort4 h0, h1;
        h0.x = f2bf_rne(x0.x); h0.y = f2bf_rne(x0.y);
        h0.z = f2bf_rne(x0.z); h0.w = f2bf_rne(x0.w);
        h1.x = f2bf_rne(x1.x); h1.y = f2bf_rne(x1.y);
        h1.z = f2bf_rne(x1.z); h1.w = f2bf_rne(x1.w);
        *(ushort4*)(dst + (size_t)r * 512 + c)     = h0;
        *(ushort4*)(dst + (size_t)r * 512 + c + 4) = h1;
    }
}

// ---------------------------------------------------------------------------
// K2: all five projection GEMMs in one launch. Every operand is pre-converted
// bf16 -> staging is pure uint4 loads (no VALU converts, no fp32 traffic).
//   bid <  192 : split-precision 64x64 tiles (fp32 out)
//   bid >= 192 : token-path 64x256 tiles, hi-only bf16 (512 blocks)
// ---------------------------------------------------------------------------
__global__ __launch_bounds__(256) void gemm_all(
    const ushort* __restrict__ q_hi, const ushort* __restrict__ q_lo,
    const ushort* __restrict__ sk_hi, const ushort* __restrict__ sk_lo,
    const ushort* __restrict__ tk_bf, const ushort* __restrict__ v_bf,
    const ushort* __restrict__ wT,
    float* __restrict__ q_stat, float* __restrict__ k_stat,
    float* __restrict__ q_tokf,
    ushort* __restrict__ k_tok, ushort* __restrict__ v_projT)
{
    __shared__ ushort smem[12800];   // 25.6 KB, unioned between variants
    const int tid = threadIdx.x;
    const int bid = blockIdx.x;
    const int wave = tid >> 6, lane = tid & 63;
    const int m16 = lane & 15, quad = lane >> 4;
    const int srow = tid >> 2, schunk = tid & 3;

    if (bid < 192) {
        // ---------------- split-precision 64x64 variant ----------------
        const int z = bid >> 6, t = bid & 63;
        const int row0 = (t >> 3) * 64, col0 = (t & 7) * 64;
        const ushort* Ah = (z == 1) ? sk_hi : q_hi;
        const ushort* Al = (z == 1) ? sk_lo : q_lo;
        const ushort* Bh = wT + (size_t)z * 524288;
        const ushort* Bl = Bh + 262144;
        float* C = (z == 0) ? q_stat : (z == 1) ? k_stat : q_tokf;

        ushort* As_hi = smem;            // [64][40]
        ushort* As_lo = smem + 2560;
        ushort* Bs_hi = smem + 5120;
        ushort* Bs_lo = smem + 7680;
        const int wm = wave & 1, wn = wave >> 1;

        f32x4 acc[2][2];
        #pragma unroll
        for (int i = 0; i < 2; ++i)
            #pragma unroll
            for (int j = 0; j < 2; ++j)
                #pragma unroll
                for (int r = 0; r < 4; ++r) acc[i][j][r] = 0.f;

        for (int k0 = 0; k0 < 512; k0 += 32) {
            const size_t aoff = (size_t)(row0 + srow) * 512 + k0 + schunk * 8;
            const size_t boff = (size_t)(col0 + srow) * 512 + k0 + schunk * 8;
            *(uint4*)&As_hi[srow * 40 + schunk * 8] = *(const uint4*)(Ah + aoff);
            *(uint4*)&Bs_hi[srow * 40 + schunk * 8] = *(const uint4*)(Bh + boff);
            *(uint4*)&As_lo[srow * 40 + schunk * 8] = *(const uint4*)(Al + aoff);
            *(uint4*)&Bs_lo[srow * 40 + schunk * 8] = *(const uint4*)(Bl + boff);
            __syncthreads();

            bf16x8 af[2], bfv[2], afl[2], bfl[2];
            #pragma unroll
            for (int i = 0; i < 2; ++i) {
                af[i]  = *(const bf16x8*)&As_hi[(wm * 32 + i * 16 + m16) * 40 + quad * 8];
                bfv[i] = *(const bf16x8*)&Bs_hi[(wn * 32 + i * 16 + m16) * 40 + quad * 8];
                afl[i] = *(const bf16x8*)&As_lo[(wm * 32 + i * 16 + m16) * 40 + quad * 8];
                bfl[i] = *(const bf16x8*)&Bs_lo[(wn * 32 + i * 16 + m16) * 40 + quad * 8];
            }
            #pragma unroll
            for (int i = 0; i < 2; ++i)
                #pragma unroll
                for (int j = 0; j < 2; ++j) {
                    acc[i][j] = __builtin_amdgcn_mfma_f32_16x16x32_bf16(af[i],  bfv[j], acc[i][j], 0, 0, 0);
                    acc[i][j] = __builtin_amdgcn_mfma_f32_16x16x32_bf16(af[i],  bfl[j], acc[i][j], 0, 0, 0);
                    acc[i][j] = __builtin_amdgcn_mfma_f32_16x16x32_bf16(afl[i], bfv[j], acc[i][j], 0, 0, 0);
                }
            __syncthreads();
        }

        #pragma unroll
        for (int i = 0; i < 2; ++i)
            #pragma unroll
            for (int j = 0; j < 2; ++j) {
                int r0 = row0 + wm * 32 + i * 16 + quad * 4;
                int c = col0 + wn * 32 + j * 16 + m16;
                #pragma unroll
                for (int reg = 0; reg < 4; ++reg)
                    C[(size_t)(r0 + reg) * 512 + c] = acc[i][j][reg];
            }
    } else {
        // ---------------- token-path 64x256 variant (hi only) ----------------
        const int u = bid - 192;
        const int z2 = u >> 8, vv = u & 255;
        const int col0 = (vv & 1) * 256, row0 = (vv >> 1) * 64;
        const ushort* A = z2 ? v_bf : tk_bf;        // dense bf16 [8192][512]
        const ushort* Bh = wT + (size_t)(z2 ? 4 : 3) * 524288;

        ushort* As = smem;            // [64][40]
        ushort* Bs = smem + 2560;     // [256][40]

        f32x4 acc[4][4];
        #pragma unroll
        for (int i = 0; i < 4; ++i)
            #pragma unroll
            for (int j = 0; j < 4; ++j)
                #pragma unroll
                for (int rr = 0; rr < 4; ++rr) acc[i][j][rr] = 0.f;

        for (int k0 = 0; k0 < 512; k0 += 32) {
            *(uint4*)&As[srow * 40 + schunk * 8] =
                *(const uint4*)(A + (size_t)(row0 + srow) * 512 + k0 + schunk * 8);
            #pragma unroll
            for (int i = 0; i < 4; ++i) {
                int v = tid + i * 256;
                int brow = v >> 2, bchunk = v & 3;
                *(uint4*)&Bs[brow * 40 + bchunk * 8] =
                    *(const uint4*)(Bh + (size_t)(col0 + brow) * 512 + k0 + bchunk * 8);
            }
            __syncthreads();

            bf16x8 af[4], bf[4];
            #pragma unroll
            for (int i = 0; i < 4; ++i) {
                af[i] = *(const bf16x8*)&As[(i * 16 + m16) * 40 + quad * 8];
                bf[i] = *(const bf16x8*)&Bs[(wave * 64 + i * 16 + m16) * 40 + quad * 8];
            }
            #pragma unroll
            for (int i = 0; i < 4; ++i)
                #pragma unroll
                for (int j = 0; j < 4; ++j)
                    acc[i][j] = __builtin_amdgcn_mfma_f32_16x16x32_bf16(af[i], bf[j], acc[i][j], 0, 0, 0);
            __syncthreads();
        }

        #pragma unroll
        for (int i = 0; i < 4; ++i)
            #pragma unroll
            for (int j = 0; j < 4; ++j) {
                int rg = row0 + i * 16 + quad * 4;
                int c = col0 + wave * 64 + j * 16 + m16;
                if (z2 == 0) {
                    #pragma unroll
                    for (int reg = 0; reg < 4; ++reg)
                        k_tok[(size_t)(rg + reg) * 512 + c] = f2bf_rne(acc[i][j][reg]);
                } else {
                    int bb2 = rg >> 10, st = rg & 1023;
                    int hh = c >> 6, dd = c & 63;
                    ushort4 o4;
                    o4.x = f2bf_rne(acc[i][j][0]);
                    o4.y = f2bf_rne(acc[i][j][1]);
                    o4.z = f2bf_rne(acc[i][j][2]);
                    o4.w = f2bf_rne(acc[i][j][3]);
                    *(ushort4*)(v_projT + (((size_t)((bb2 * 8 + hh) * 64 + dd)) << 10) + st) = o4;
                }
            }
    }
}

// ---------------------------------------------------------------------------
// K3: stat scores + valid-len mask + top-8 + softmax -> DENSE stat_w
// [4096][64]. One wave per (b,h,q). (verified)
// ---------------------------------------------------------------------------
__global__ __launch_bounds__(64) void stat_topk(
    const float* __restrict__ q_stat, const float* __restrict__ k_stat,
    const int* __restrict__ valid_lens,
    float* __restrict__ stat_wd)
{
    const int bid = blockIdx.x;           // b*512 + h*64 + q
    const int b = bid >> 9;
    const int hq = bid & 511;
    const int h = hq >> 6;
    const int q = hq & 63;
    const int lane = threadIdx.x;         // segment index s

    __shared__ float sq[64];
    sq[lane] = q_stat[(b * 64 + q) * 512 + h * 64 + lane];
    __syncthreads();

    const float4* kr = (const float4*)(k_stat + (b * 64 + lane) * 512 + h * 64);
    const float4* sq4 = (const float4*)sq;
    float sc = 0.f;
    #pragma unroll
    for (int i = 0; i < 16; ++i) {
        float4 a = sq4[i], kk = kr[i];
        sc += a.x * kk.x + a.y * kk.y + a.z * kk.z + a.w * kk.w;
    }
    sc *= 0.125f;
    if (lane >= valid_lens[b]) sc = -1e6f;

    const float sc_keep = sc;
    float my = sc;
    bool picked = false;
    float m0 = 0.f, den = 0.f;
    #pragma unroll
    for (int j = 0; j < STAT_K; ++j) {
        float v = my;
        int idx = lane;
        #pragma unroll
        for (int off = 32; off > 0; off >>= 1) {
            float ov = __shfl_down(v, off);
            int   oi = __shfl_down(idx, off);
            if (ov > v || (ov == v && oi < idx)) { v = ov; idx = oi; }
        }
        v = __shfl(v, 0);
        idx = __shfl(idx, 0);
        if (j == 0) m0 = v;
        den += __expf(v - m0);
        if (lane == idx) { my = -3e38f; picked = true; }
    }
    stat_wd[(size_t)bid * 64 + lane] = picked ? __expf(sc_keep - m0) / den : 0.f;
}

// ---------------------------------------------------------------------------
// K4: dense MFMA token attention, chunk-parallel (verified round 5/7).
// One block per (b,h,16-q slice,16-seg chunk) -> 1024 blocks, 4 waves.
// ---------------------------------------------------------------------------
__global__ __launch_bounds__(256) void tok_attend(
    const float* __restrict__ q_tokf, const ushort* __restrict__ k_tok,
    const ushort* __restrict__ v_projT, const float* __restrict__ stat_wd,
    float* __restrict__ part)
{
    const int bid = blockIdx.x;
    const int ch = bid & 3, qb = (bid >> 2) & 3, bh = bid >> 4;
    const int b = bh >> 3, h = bh & 7;
    const int tid = threadIdx.x, wave = tid >> 6, lane = tid & 63;
    const int l15 = lane & 15, g = lane >> 4;
    const int q0 = qb * 16;

    __shared__ ushort qs_hi[16][72], qs_lo[16][72];       // q_tok hi/lo
    __shared__ float  sw16[16][17];                       // stat_w slice
    __shared__ ushort comb_hi[16][264], comb_lo[16][264]; // [q][st], swizzled

    // ---- stage q slice (fp32 -> hi/lo bf16) and stat_w slice
    {
        const int qq = tid >> 4, c = (tid & 15) * 4;
        float4 x = *(const float4*)(q_tokf + (size_t)(b * 64 + q0 + qq) * 512 + h * 64 + c);
        ushort4 hx, lx;
        hx.x = f2bf_rne(x.x); lx.x = f2bf_rne(x.x - bf2f(hx.x));
        hx.y = f2bf_rne(x.y); lx.y = f2bf_rne(x.y - bf2f(hx.y));
        hx.z = f2bf_rne(x.z); lx.z = f2bf_rne(x.z - bf2f(hx.z));
        hx.w = f2bf_rne(x.w); lx.w = f2bf_rne(x.w - bf2f(hx.w));
        *(ushort4*)&qs_hi[qq][c] = hx;
        *(ushort4*)&qs_lo[qq][c] = lx;
        sw16[tid >> 4][tid & 15] =
            stat_wd[(size_t)bh * 4096 + (q0 + (tid >> 4)) * 64 + ch * 16 + (tid & 15)];
    }
    __syncthreads();

    const int swz = (l15 & 7) << 4;

    // ---- QK: this wave computes 4 segments (64 st) x 16 q
    const int sbase = ch * 16 + wave * 4;
    f32x4 sc[4];
    #pragma unroll
    for (int mt = 0; mt < 4; ++mt)
        #pragma unroll
        for (int rr = 0; rr < 4; ++rr) sc[mt][rr] = 0.f;

    #pragma unroll
    for (int ks2 = 0; ks2 < 2; ++ks2) {
        bf16x8 bhf = *(const bf16x8*)&qs_hi[l15][ks2 * 32 + g * 8];
        bf16x8 blf = *(const bf16x8*)&qs_lo[l15][ks2 * 32 + g * 8];
        #pragma unroll
        for (int mt = 0; mt < 4; ++mt) {
            const ushort* kp = k_tok +
                (size_t)(b * 1024 + (sbase + mt) * 16 + l15) * 512 + h * 64 + ks2 * 32 + g * 8;
            bf16x8 a = *(const bf16x8*)kp;
            sc[mt] = __builtin_amdgcn_mfma_f32_16x16x32_bf16(a, bhf, sc[mt], 0, 0, 0);
            sc[mt] = __builtin_amdgcn_mfma_f32_16x16x32_bf16(a, blf, sc[mt], 0, 0, 0);
        }
    }

    // ---- per-segment softmax over 16 tokens + comb write (hi/lo)
    #pragma unroll
    for (int mt = 0; mt < 4; ++mt) {
        float e0 = __expf(sc[mt][0] * 0.125f);
        float e1 = __expf(sc[mt][1] * 0.125f);
        float e2 = __expf(sc[mt][2] * 0.125f);
        float e3 = __expf(sc[mt][3] * 0.125f);
        float den = e0 + e1 + e2 + e3;
        den += __shfl_xor(den, 16);
        den += __shfl_xor(den, 32);
        float scl = sw16[l15][wave * 4 + mt] / den;
        ushort4 hx, lx;
        float c0 = e0 * scl; hx.x = f2bf_rne(c0); lx.x = f2bf_rne(c0 - bf2f(hx.x));
        float c1 = e1 * scl; hx.y = f2bf_rne(c1); lx.y = f2bf_rne(c1 - bf2f(hx.y));
        float c2 = e2 * scl; hx.z = f2bf_rne(c2); lx.z = f2bf_rne(c2 - bf2f(hx.z));
        float c3 = e3 * scl; hx.w = f2bf_rne(c3); lx.w = f2bf_rne(c3 - bf2f(hx.w));
        int colb = (((wave * 4 + mt) * 16 + g * 4) * 2) ^ swz;
        *(ushort4*)((char*)&comb_hi[l15][0] + colb) = hx;
        *(ushort4*)((char*)&comb_lo[l15][0] + colb) = lx;
    }
    __syncthreads();

    // ---- PV over this chunk (K = 256 st); wave owns 16-d block
    f32x4 accd;
    #pragma unroll
    for (int rr = 0; rr < 4; ++rr) accd[rr] = 0.f;

    #pragma unroll
    for (int ks2 = 0; ks2 < 8; ++ks2) {
        const ushort* vp = v_projT +
            ((size_t)(bh * 64 + wave * 16 + l15) << 10) + ch * 256 + ks2 * 32 + g * 8;
        bf16x8 a = *(const bf16x8*)vp;
        int colb = ((ks2 * 32 + g * 8) * 2) ^ swz;
        bf16x8 bhf = *(const bf16x8*)((const char*)&comb_hi[l15][0] + colb);
        bf16x8 blf = *(const bf16x8*)((const char*)&comb_lo[l15][0] + colb);
        accd = __builtin_amdgcn_mfma_f32_16x16x32_bf16(a, bhf, accd, 0, 0, 0);
        accd = __builtin_amdgcn_mfma_f32_16x16x32_bf16(a, blf, accd, 0, 0, 0);
    }

    // ---- partial write: lane holds d = wave*16 + g*4 + rr, q = q0 + l15
    *(f32x4*)(part + ((size_t)(ch * 512 + b * 64 + q0 + l15) * 512)
                    + h * 64 + wave * 16 + g * 4) = accd;
}

// ---------------------------------------------------------------------------
// K5: out = (sum_ch part[ch]) @ Wo(hi/lo planes), 512x512x512 -> fp32.
// (verified round 5/7)
// ---------------------------------------------------------------------------
__global__ __launch_bounds__(256) void gemm_out(
    const float* __restrict__ part,
    const ushort* __restrict__ Bh, const ushort* __restrict__ Bl,
    float* __restrict__ C)
{
    __shared__ ushort As[2][64][40];
    __shared__ ushort Bs[2][64][40];
    const int tid = threadIdx.x;
    const int row0 = blockIdx.y * 64, col0 = blockIdx.x * 64;
    const int wave = tid >> 6, lane = tid & 63;
    const int wm = wave & 1, wn = wave >> 1;
    const int m16 = lane & 15, quad = lane >> 4;
    const int srow = tid >> 2, schunk = tid & 3;

    f32x4 acc[2][2];
    #pragma unroll
    for (int i = 0; i < 2; ++i)
        #pragma unroll
        for (int j = 0; j < 2; ++j)
            #pragma unroll
            for (int r = 0; r < 4; ++r) acc[i][j][r] = 0.f;

    for (int k0 = 0; k0 < 512; k0 += 32) {
        // A: sum 4 chunk partials, split hi/lo
        const float* pb = part + (size_t)(row0 + srow) * 512 + k0 + schunk * 8;
        float s[8];
        #pragma unroll
        for (int e = 0; e < 8; ++e) s[e] = 0.f;
        #pragma unroll
        for (int c = 0; c < 4; ++c) {
            const float4* p4 = (const float4*)(pb + (size_t)c * 262144);
            float4 a0 = p4[0], a1 = p4[1];
            s[0] += a0.x; s[1] += a0.y; s[2] += a0.z; s[3] += a0.w;
            s[4] += a1.x; s[5] += a1.y; s[6] += a1.z; s[7] += a1.w;
        }
        ushort hv[8], lv[8];
        #pragma unroll
        for (int e = 0; e < 8; ++e) {
            hv[e] = f2bf_rne(s[e]);
            lv[e] = f2bf_rne(s[e] - bf2f(hv[e]));
        }
        *(ushort4*)&As[0][srow][schunk * 8]     = *(ushort4*)&hv[0];
        *(ushort4*)&As[0][srow][schunk * 8 + 4] = *(ushort4*)&hv[4];
        *(ushort4*)&As[1][srow][schunk * 8]     = *(ushort4*)&lv[0];
        *(ushort4*)&As[1][srow][schunk * 8 + 4] = *(ushort4*)&lv[4];

        const size_t boff = (size_t)(col0 + srow) * 512 + k0 + schunk * 8;
        *(uint4*)&Bs[0][srow][schunk * 8] = *(const uint4*)(Bh + boff);
        *(uint4*)&Bs[1][srow][schunk * 8] = *(const uint4*)(Bl + boff);
        __syncthreads();

        bf16x8 af[2], bf[2], afl[2], bfl[2];
        #pragma unroll
        for (int i = 0; i < 2; ++i) {
            af[i]  = *(const bf16x8*)&As[0][wm * 32 + i * 16 + m16][quad * 8];
            bf[i]  = *(const bf16x8*)&Bs[0][wn * 32 + i * 16 + m16][quad * 8];
            afl[i] = *(const bf16x8*)&As[1][wm * 32 + i * 16 + m16][quad * 8];
            bfl[i] = *(const bf16x8*)&Bs[1][wn * 32 + i * 16 + m16][quad * 8];
        }
        #pragma unroll
        for (int i = 0; i < 2; ++i)
            #pragma unroll
            for (int j = 0; j < 2; ++j) {
                acc[i][j] = __builtin_amdgcn_mfma_f32_16x16x32_bf16(af[i], bf[j], acc[i][j], 0, 0, 0);
                acc[i][j] = __builtin_amdgcn_mfma_f32_16x16x32_bf16(af[i], bfl[j], acc[i][j], 0, 0, 0);
                acc[i][j] = __builtin_amdgcn_mfma_f32_16x16x32_bf16(afl[i], bf[j], acc[i][j], 0, 0, 0);
            }
        __syncthreads();
    }

    #pragma unroll
    for (int i = 0; i < 2; ++i)
        #pragma unroll
        for (int j = 0; j < 2; ++j) {
            int r0 = row0 + wm * 32 + i * 16 + quad * 4;
            int c = col0 + wn * 32 + j * 16 + m16;
            #pragma unroll
            for (int reg = 0; reg < 4; ++reg)
                C[(size_t)(r0 + reg) * 512 + c] = acc[i][j][reg];
        }
}

extern "C" void kernel_launch(void* const* d_in, const int* in_sizes, int n_in,
                              void* d_out, int out_size, void* d_ws, size_t ws_size,
                              hipStream_t stream) {
    const float* queries    = (const float*)d_in[0];
    const float* stat_keys  = (const float*)d_in[1];
    const float* token_keys = (const float*)d_in[2];
    const float* values     = (const float*)d_in[3];
    const int*   valid_lens = (const int*)d_in[4];
    const float* Wq_stat    = (const float*)d_in[5];
    const float* Wq_token   = (const float*)d_in[6];
    const float* Wk_stat    = (const float*)d_in[7];
    const float* Wk_token   = (const float*)d_in[8];
    const float* Wv         = (const float*)d_in[9];
    const float* Wo         = (const float*)d_in[10];

    char* w = (char*)d_ws;
    ushort* wT      = (ushort*)(w + 0);          // 6 MB: 6 x (hi+lo) x 262144
    ushort* q_hi    = (ushort*)(w + 6291456);    // 512 KB
    ushort* q_lo    = q_hi + 262144;             // 512 KB
    ushort* sk_hi   = (ushort*)(w + 7340032);    // 512 KB
    ushort* sk_lo   = sk_hi + 262144;            // 512 KB
    float*  q_stat  = (float*)(w + 8388608);     // 1 MB fp32 [512][512]
    float*  k_stat  = (float*)(w + 9437184);     // 1 MB
    float*  q_tokf  = (float*)(w + 10485760);    // 1 MB
    ushort* k_tok   = (ushort*)(w + 11534336);   // 8 MB bf16 [8192][512]
    ushort* v_projT = (ushort*)(w + 19922944);   // 8 MB bf16 [64][64][1024]
    ushort* tk_bf   = (ushort*)(w + 28311552);   // 8 MB bf16 [8192][512]
    ushort* v_bf    = (ushort*)(w + 36700160);   // 8 MB bf16 [8192][512]
    float*  stat_wd = (float*)(w + 45088768);    // 1 MB dense [4096][64]
    float*  part    = (float*)(w + 46137344);    // 4 MB fp32 [4][512][512]

    // weight order in wT: 0=Wq_stat 1=Wk_stat 2=Wq_token 3=Wk_token 4=Wv 5=Wo
    ushort* wo_h = wT + 5 * 524288, *wo_l = wo_h + 262144;

    // K1: all conversions (weights, q/sk split, token bf16 copies)
    conv_all<<<6144, 256, 0, stream>>>(
        Wq_stat, Wk_stat, Wq_token, Wk_token, Wv, Wo,
        queries, stat_keys, token_keys, values,
        wT, q_hi, q_lo, sk_hi, sk_lo, tk_bf, v_bf);

    // K2: all five projection GEMMs, pure-bf16 staging (704 blocks)
    gemm_all<<<704, 256, 0, stream>>>(
        q_hi, q_lo, sk_hi, sk_lo, tk_bf, v_bf, wT,
        q_stat, k_stat, q_tokf, k_tok, v_projT);

    // K3: stat top-8 + softmax -> dense stat_w
    stat_topk<<<4096, 64, 0, stream>>>(q_stat, k_stat, valid_lens, stat_wd);

    // K4: chunk-parallel dense token attention -> fp32 partials
    tok_attend<<<1024, 256, 0, stream>>>(q_tokf, k_tok, v_projT, stat_wd, part);

    // K5: output projection (sums partials in A-staging)
    gemm_out<<<dim3(8, 8), 256, 0, stream>>>(part, wo_h, wo_l, (float*)d_out);
}